// Round 9
// baseline (64.094 us; speedup 1.0000x reference)
//
#include <hip/hip_runtime.h>

// Geometric product over 3D PGA, 16-component multivectors.
// C[..., k] = sum_ij A[...,i] * B[...,j] * cayley[k,i,j]
// Cayley table rebuilt at COMPILE TIME (mirrors the reference Python); the
// 16x16 double loop constant-folds to the 192 nonzero +-1 fp32 FMAs.
//
// R9 = R7 (best: coalesced I/O + swizzled LDS transpose + NT stores) with a
// SINGLE 16KB LDS buffer time-multiplexed across three transpose phases
// (A, then B, then C-out), instead of two 16KB buffers live at once.
//   - all 8 global dwordx4 loads issue up-front into registers, so HBM
//     latency overlaps the phase-A/B LDS traffic;
//   - LDS/block 32KB -> 16KB lifts the occupancy cap from 5 blocks/CU to
//     min(LDS 10, threads 8, VGPR ~7) blocks/CU; R7 measured occupancy 36%
//     with VALUBusy 13% and HBM at 68% of achievable => latency-bound, so
//     more resident waves = more loads in flight = higher sustained BW.
//   - 5 barriers instead of 2 (R5 established barriers are not the limiter).
// R8 lesson: DPP quad_perm transpose produced all-zero output (unexplained);
// reverted to the LDS transpose. R7 lesson: NT stores -15us (keep).
// R5 lesson: ALL global I/O stays coalesced.

namespace {

typedef float f32x4 __attribute__((ext_vector_type(4)));

struct CayleyLUT {
    int idx[16][16];
    int sgn[16][16];
};

constexpr CayleyLUT make_lut() {
    CayleyLUT L{};
    constexpr int MASK[16] = {0, 2, 4, 8, 1, 6, 10, 12, 3, 5, 9, 14, 7, 11, 13, 15};
    constexpr int SIGN[16] = {1, 1, 1, 1, 1, 1, 1, 1, -1, -1, -1, 1, 1, 1, 1, -1};
    for (int i = 0; i < 16; ++i) {
        for (int j = 0; j < 16; ++j) {
            L.idx[i][j] = 0;
            L.sgn[i][j] = 0;
            if (MASK[i] & MASK[j] & 1) continue;  // shared null e0 -> vanishes
            const int rm = MASK[i] ^ MASK[j];
            int k = 0;
            for (int t = 0; t < 16; ++t)
                if (MASK[t] == rm) k = t;
            int s = 1;
            for (int bit = 0; bit < 4; ++bit) {
                if ((MASK[i] >> bit) & 1) {
                    int lower = MASK[j] & ((1 << bit) - 1);
                    int c = 0;
                    for (int x = lower; x; x >>= 1) c += x & 1;
                    if (c & 1) s = -s;
                }
            }
            L.idx[i][j] = k;
            L.sgn[i][j] = SIGN[i] * SIGN[j] * s * SIGN[k];
        }
    }
    return L;
}

constexpr CayleyLUT LUT = make_lut();

__device__ __forceinline__ int slot(int m, int q) {
    // Float offset of quad q of MV m in the swizzled LDS tile.
    // Conflict-free for both the staging (m=f>>2,q=f&3) and compute
    // (m=t, q fixed) patterns — enumerated in R4.
    return m * 16 + ((q ^ ((m >> 1) & 3)) << 2);
}

__device__ __forceinline__ void gp_compute(const float* a, const float* b, float* c) {
#pragma unroll
    for (int k = 0; k < 16; ++k) c[k] = 0.0f;
#pragma unroll
    for (int i = 0; i < 16; ++i) {
#pragma unroll
        for (int j = 0; j < 16; ++j) {
            const int s = LUT.sgn[i][j];
            if (s != 0) {
                const int k = LUT.idx[i][j];
                c[k] = fmaf(s > 0 ? a[i] : -a[i], b[j], c[k]);
            }
        }
    }
}

__global__ __launch_bounds__(256) void gp_kernel(const float* __restrict__ A,
                                                 const float* __restrict__ B,
                                                 float* __restrict__ C,
                                                 long long n_mv) {
    __shared__ float s[256 * 16];  // 16 KiB, time-multiplexed A -> B -> C
    const int t = threadIdx.x;
    const long long base_mv = (long long)blockIdx.x * 256;
    const bool full = (base_mv + 256 <= n_mv);
    const int mv_here = full ? 256 : (int)(n_mv - base_mv);
    const int nf4 = mv_here * 4;
    const bool act = full || (t < mv_here);

    const f32x4* __restrict__ A4 = reinterpret_cast<const f32x4*>(A) + base_mv * 4;
    const f32x4* __restrict__ B4 = reinterpret_cast<const f32x4*>(B) + base_mv * 4;
    f32x4* __restrict__ C4 = reinterpret_cast<f32x4*>(C) + base_mv * 4;

    // ---- issue ALL global loads up front (8 outstanding dwordx4/thread);
    //      latency overlaps the phase-A/B LDS transposes below ----
    f32x4 va[4], vb[4];
    if (full) {
#pragma unroll
        for (int r = 0; r < 4; ++r) {
            const int f = t + 256 * r;
            va[r] = A4[f];
            vb[r] = B4[f];
        }
    } else {
#pragma unroll
        for (int r = 0; r < 4; ++r) {
            const int f = t + 256 * r;
            va[r] = 0;
            vb[r] = 0;
            if (f < nf4) {
                va[r] = A4[f];
                vb[r] = B4[f];
            }
        }
    }

    // ---- phase A: transpose A through LDS ----
#pragma unroll
    for (int r = 0; r < 4; ++r) {
        const int f = t + 256 * r;
        if (full || f < nf4) *reinterpret_cast<f32x4*>(&s[slot(f >> 2, f & 3)]) = va[r];
    }
    __syncthreads();
    float a[16];
    if (act) {
#pragma unroll
        for (int q = 0; q < 4; ++q) {
            const f32x4 v = *reinterpret_cast<const f32x4*>(&s[slot(t, q)]);
#pragma unroll
            for (int w = 0; w < 4; ++w) a[4 * q + w] = v[w];
        }
    }
    __syncthreads();

    // ---- phase B: transpose B through the same buffer ----
#pragma unroll
    for (int r = 0; r < 4; ++r) {
        const int f = t + 256 * r;
        if (full || f < nf4) *reinterpret_cast<f32x4*>(&s[slot(f >> 2, f & 3)]) = vb[r];
    }
    __syncthreads();
    float b[16];
    if (act) {
#pragma unroll
        for (int q = 0; q < 4; ++q) {
            const f32x4 v = *reinterpret_cast<const f32x4*>(&s[slot(t, q)]);
#pragma unroll
            for (int w = 0; w < 4; ++w) b[4 * q + w] = v[w];
        }
    }
    __syncthreads();

    // ---- compute + phase C: inverse transpose of the result ----
    if (act) {
        float c[16];
        gp_compute(a, b, c);
#pragma unroll
        for (int q = 0; q < 4; ++q) {
            f32x4 v;
#pragma unroll
            for (int w = 0; w < 4; ++w) v[w] = c[4 * q + w];
            *reinterpret_cast<f32x4*>(&s[slot(t, q)]) = v;
        }
    }
    __syncthreads();
#pragma unroll
    for (int r = 0; r < 4; ++r) {
        const int f = t + 256 * r;
        if (full || f < nf4) {
            const f32x4 v = *reinterpret_cast<const f32x4*>(&s[slot(f >> 2, f & 3)]);
            __builtin_nontemporal_store(v, &C4[f]);
        }
    }
}

}  // namespace

extern "C" void kernel_launch(void* const* d_in, const int* in_sizes, int n_in,
                              void* d_out, int out_size, void* d_ws, size_t ws_size,
                              hipStream_t stream) {
    const float* A = (const float*)d_in[0];
    const float* B = (const float*)d_in[1];
    float* C = (float*)d_out;
    const long long n_mv = (long long)in_sizes[0] / 16;
    const int nblocks = (int)((n_mv + 255) / 256);
    gp_kernel<<<nblocks, 256, 0, stream>>>(A, B, C, n_mv);
}